// Round 11
// baseline (353.656 us; speedup 1.0000x reference)
//
#include <hip/hip_runtime.h>
#include <hip/hip_bf16.h>
#include <stdint.h>

typedef __attribute__((ext_vector_type(8))) short short8;   // 8 bf16 (x32 mfma A/B)
typedef __attribute__((ext_vector_type(4))) short short4v;  // 4 bf16 (x16 mfma A/B)
typedef __attribute__((ext_vector_type(4))) float f32x4;
typedef __attribute__((ext_vector_type(4))) unsigned short us4;
typedef unsigned short ushort_t;

#define LDS_AS __attribute__((address_space(3)))
#define GLB_AS __attribute__((address_space(1)))

__device__ __forceinline__ void gload_lds16(const void* g, void* l) {
    __builtin_amdgcn_global_load_lds((const GLB_AS uint32_t*)g, (LDS_AS uint32_t*)l, 16, 0, 0);
}

__device__ __forceinline__ unsigned short f2bf(float f) {
    union { float f; uint32_t u; } v; v.f = f;
    uint32_t r = v.u + 0x7FFFu + ((v.u >> 16) & 1u);   // RNE
    return (unsigned short)(r >> 16);
}

__device__ __forceinline__ float fexp2(float x) {
#if __has_builtin(__builtin_amdgcn_exp2f)
    return __builtin_amdgcn_exp2f(x);
#else
    return exp2f(x);
#endif
}

__device__ __forceinline__ uint32_t fbits(float f) {
    union { float f; uint32_t u; } v; v.f = f; return v.u;
}

__device__ __forceinline__ f32x4 mfma32(short8 a, short8 b, f32x4 c) {
    return __builtin_amdgcn_mfma_f32_16x16x32_bf16(a, b, c, 0, 0, 0);
}
__device__ __forceinline__ f32x4 mfma16(short4v a, short4v b, f32x4 c) {
    return __builtin_amdgcn_mfma_f32_16x16x16bf16_1k(a, b, c, 0, 0, 0);
}

// read one MFMA frag (16B) from an XOR-swizzled [rows][64 bf16] LDS tile
__device__ __forceinline__ short8 lds_frag(const char* base, int row, int kc) {
    int byte = row * 128 + ((kc ^ (row & 7)) << 4);
    return *(const short8*)(base + byte);
}

// ---------------- fused fp32 -> bf16 conversion (7 tensors, one launch) ----------------
__global__ __launch_bounds__(256) void cvt_all(
    const float* p0, const float* p1, const float* p2, const float* p3,
    const float* p4, const float* p5, const float* p6,
    ushort_t* o0, ushort_t* o1, ushort_t* o2, ushort_t* o3,
    ushort_t* o4, ushort_t* o5, ushort_t* o6) {
    int z = blockIdx.y;
    const float* in = z == 0 ? p0 : z == 1 ? p1 : z == 2 ? p2 : z == 3 ? p3 : z == 4 ? p4 : z == 5 ? p5 : p6;
    ushort_t* out = z == 0 ? o0 : z == 1 ? o1 : z == 2 ? o2 : z == 3 ? o3 : z == 4 ? o4 : z == 5 ? o5 : o6;
    int n4 = z < 3 ? 1048576 : 262144;
    int i = blockIdx.x * 256 + threadIdx.x;
    int stride = gridDim.x * 256;
    for (; i < n4; i += stride) {
        float4 f = ((const float4*)in)[i];
        us4 o;
        o[0] = f2bf(f.x); o[1] = f2bf(f.y); o[2] = f2bf(f.z); o[3] = f2bf(f.w);
        ((us4*)out)[i] = o;
    }
}

// ---------------- mask bit-packing, transposed layout [b][kvblk(32)][q(2048)] ----------------
__global__ __launch_bounds__(256) void pack_mask(const int* __restrict__ mask,
                                                 unsigned long long* __restrict__ out) {
    int i = blockIdx.x * 256 + threadIdx.x;          // bit index over [b][q][k]
    unsigned long long bits = __ballot(mask[i] != 0);
    if ((threadIdx.x & 63) == 0) {
        int k = i & 2047, q = (i >> 11) & 2047, b = i >> 22;
        out[((size_t)b * 32 + (k >> 6)) * 2048 + q] = bits;
    }
}

// ---------------- GEMM core: (MI*32)x128 tile, K=1024, double-buffered prefetch ----------
// Issue stage(kt+1) BEFORE compute(kt); one barrier per iter. No setprio here: barrier-
// locked GEMM waves gain nothing from priority (m190 regime).
template<int MI>
__device__ __forceinline__ void gemm_core(const ushort_t* Ab, const ushort_t* Wb,
                                          char* lds, int tid, f32x4 acc[MI][4]) {
    constexpr int K = 1024;
    constexpr int ABYTES = MI * 4096;          // A tile: MI*32 rows x 128B
    constexpr int TILE = ABYTES + 16384;       // + B tile (128 rows x 128B)
    int lane = tid & 63, wid = tid >> 6;
    int cl = lane & 15, gr = lane >> 4;
    int wm = (wid >> 1) * (MI * 16), wn = (wid & 1) * 64;
#pragma unroll
    for (int i = 0; i < MI; ++i)
#pragma unroll
        for (int j = 0; j < 4; ++j) acc[i][j] = (f32x4)0.0f;

    // hoisted per-thread staging offsets (only k0 varies per iter)
    int aOff[MI], aDst[MI], bOff[4], bDst[4];
#pragma unroll
    for (int iss = 0; iss < MI; ++iss) {
        int c = iss * 256 + tid;
        int r = c >> 3, kc = (c & 7) ^ (r & 7);
        aOff[iss] = r * K + kc * 8;
        aDst[iss] = c * 16;
    }
#pragma unroll
    for (int iss = 0; iss < 4; ++iss) {
        int c = iss * 256 + tid;
        int r = c >> 3, kc = (c & 7) ^ (r & 7);
        bOff[iss] = r * K + kc * 8;
        bDst[iss] = c * 16;
    }

    auto stage = [&](int kt, char* dst) {
        int k0 = kt * 64;
#pragma unroll
        for (int iss = 0; iss < MI; ++iss)
            gload_lds16(Ab + aOff[iss] + k0, dst + aDst[iss]);
#pragma unroll
        for (int iss = 0; iss < 4; ++iss)
            gload_lds16(Wb + bOff[iss] + k0, dst + ABYTES + bDst[iss]);
    };

    stage(0, lds);
    __syncthreads();

    for (int kt = 0; kt < K / 64; ++kt) {
        char* cb = lds + (kt & 1) * TILE;
        if (kt < K / 64 - 1) stage(kt + 1, lds + ((kt + 1) & 1) * TILE);
        char* cA = cb;
        char* cW = cb + ABYTES;
#pragma unroll
        for (int ks = 0; ks < 2; ++ks) {
            short8 af[MI], wf[4];
#pragma unroll
            for (int t = 0; t < MI; ++t)
                af[t] = lds_frag(cA, wm + t * 16 + cl, ks * 4 + gr);
#pragma unroll
            for (int t = 0; t < 4; ++t)
                wf[t] = lds_frag(cW, wn + t * 16 + cl, ks * 4 + gr);
#pragma unroll
            for (int i = 0; i < MI; ++i)
#pragma unroll
                for (int j = 0; j < 4; ++j)
                    acc[i][j] = mfma32(af[i], wf[j], acc[i][j]);
        }
        __syncthreads();   // drains prefetch (already landed under compute) + guards buf reuse
    }
}

// mode 0: bf16 out head-major [b,h,s,d]; mode 1: bf16 out [b,h,d,s]; mode 2: fp32 row-major
// Tile: (MI*32)x128. Grid (8, M/(MI*32), z). Bijective XCD swizzle over the flat block id.
template<int MI>
__global__ __launch_bounds__(256, 3)
void gemm3(const ushort_t* A0, const ushort_t* A1, const ushort_t* A2,
           const ushort_t* W0, const ushort_t* W1, const ushort_t* W2,
           const float* B0, const float* B1, const float* B2,
           void* O0, void* O1, void* O2, int mode_ovr, float scl0) {
    __shared__ char lds[2 * (MI * 4096 + 16384)];

    // XCD swizzle: consecutive logical ids land on one XCD; bx fastest (shared A panel)
    int gx = gridDim.x, gy = gridDim.y;
    int nwg = gx * gy * gridDim.z;
    int bid = blockIdx.x + gx * (blockIdx.y + gy * blockIdx.z);
    int nb = (bid & 7) * (nwg >> 3) + (bid >> 3);
    int bx = nb % gx;
    int t2 = nb / gx;
    int by = t2 % gy;
    int z = t2 / gy;

    const ushort_t* A = z == 0 ? A0 : z == 1 ? A1 : A2;
    const ushort_t* W = z == 0 ? W0 : z == 1 ? W1 : W2;
    const float* bias = z == 0 ? B0 : z == 1 ? B1 : B2;
    void* out = z == 0 ? O0 : z == 1 ? O1 : O2;
    int mode = mode_ovr >= 0 ? mode_ovr : (z == 2 ? 1 : 0);
    float scl = z == 0 ? scl0 : 1.0f;

    int tid = threadIdx.x, lane = tid & 63, wid = tid >> 6;
    int cl = lane & 15, gr = lane >> 4;
    int wm = (wid >> 1) * (MI * 16), wn = (wid & 1) * 64;
    int bm = by * (MI * 32), bn = bx * 128;

    f32x4 acc[MI][4];
    gemm_core<MI>(A + (size_t)bm * 1024, W + (size_t)bn * 1024, lds, tid, acc);

#pragma unroll
    for (int j = 0; j < 4; ++j) {
        int n = bn + wn + j * 16 + cl;
        float bv = bias[n];
#pragma unroll
        for (int i = 0; i < MI; ++i) {
            int mbase = bm + wm + i * 16 + gr * 4;
            if (mode == 0) {
#pragma unroll
                for (int r = 0; r < 4; ++r) {
                    int m = mbase + r;
                    float v = (acc[i][j][r] + bv) * scl;
                    size_t idx = (((size_t)((m >> 11) * 16 + (n >> 6))) * 2048 + (m & 2047)) * 64 + (n & 63);
                    ((ushort_t*)out)[idx] = f2bf(v);
                }
            } else if (mode == 1) {
                us4 pk;
#pragma unroll
                for (int r = 0; r < 4; ++r) pk[r] = f2bf(acc[i][j][r] + bv);
                size_t idx = (((size_t)((mbase >> 11) * 16 + (n >> 6))) * 64 + (n & 63)) * 2048 + (mbase & 2047);
                *(us4*)((ushort_t*)out + idx) = pk;
            } else {
#pragma unroll
                for (int r = 0; r < 4; ++r)
                    ((float*)out)[(size_t)(mbase + r) * 1024 + n] = acc[i][j][r] + bv;
            }
        }
    }
}

// ---------------- fused masked attention v9 ----------------
// grid 512 = (b,h)*16 q-tiles of 128 rows; 8 waves = 4 q-groups x 2 kv-halves.
// K fragments load DIRECTLY global->VGPR (L1/L2-hot 8KB tiles; no LDS, no barrier
// dependency). Only V goes through LDS (2 streams x 2 bufs x 8KB = 32KB staging;
// 40KB peak with merge scratch) -> 4 blocks/CU, 6 waves/SIMD target.
// Deferred softmax, in-register P, ones-column MFMA row-sums, setprio on MFMA.
__global__ __launch_bounds__(512, 6)
void attn(const ushort_t* __restrict__ Q, const ushort_t* __restrict__ Kh,
          const ushort_t* __restrict__ Vt, const unsigned long long* __restrict__ PM,
          ushort_t* __restrict__ ctx) {
    constexpr int S = 2048;
    __shared__ char lds[40960];   // [2 streams][2 bufs][V 8KB] = 32KB; merge scratch 40KB
    int tid = threadIdx.x, lane = tid & 63, wid = tid >> 6;
    int cl = lane & 15, gr = lane >> 4, c7 = cl & 7;
    int h2 = wid & 1;            // kv-half this wave computes
    int qg = wid >> 1;           // q-group 0..3

    int blk = (blockIdx.x & 7) * 64 + (blockIdx.x >> 3);
    int bh = blk >> 4, qt = blk & 15;
    int b = bh >> 4, h = bh & 15;
    const ushort_t* Qb = Q + (size_t)bh * S * 64;
    const ushort_t* Kb = Kh + (size_t)bh * S * 64;
    const ushort_t* Vb = Vt + (size_t)bh * 64 * S;
    int q0w = qt * 128 + qg * 32;

    short8 qreg[2][2];
#pragma unroll
    for (int qf = 0; qf < 2; ++qf)
#pragma unroll
        for (int ks = 0; ks < 2; ++ks)
            qreg[qf][ks] = *(const short8*)(Qb + (size_t)(q0w + qf * 16 + cl) * 64 + ks * 32 + gr * 8);

    f32x4 acc[2][4];
    f32x4 accl[2];
#pragma unroll
    for (int qf = 0; qf < 2; ++qf) {
        accl[qf] = (f32x4)0.0f;
#pragma unroll
        for (int df = 0; df < 4; ++df) acc[qf][df] = (f32x4)0.0f;
    }

    // V staging: threads 0-255 feed stream 0 (kv 0..15), 256-511 feed stream 1 (kv 16..31)
    int hs = tid >> 8, stid = tid & 255;
    int vOff[2], dstL[2];
#pragma unroll
    for (int iss = 0; iss < 2; ++iss) {
        int L = iss * 256 + stid;
        int r = L >> 3, c = (L & 7) ^ (r & 7);
        vOff[iss] = r * S + c * 8;
        dstL[iss] = L * 16;
    }
    char* sbase = lds + hs * 16384;

    // hoisted V LDS read addresses
    int aV[4];
#pragma unroll
    for (int nf = 0; nf < 4; ++nf)
        aV[nf] = cl * 128 + (((2 * nf) + (gr >> 1)) ^ c7) * 16 + (gr & 1) * 8;

    // per-wave K row base (global, direct loads): row = s0 + nf*16 + cl, d-offset gr*8
    const ushort_t* Kw = Kb + (size_t)(cl) * 64 + gr * 8;

    const unsigned long long* pmq = PM + (size_t)b * 32 * 2048 + q0w + cl;

    short4v ones;
#pragma unroll
    for (int r = 0; r < 4; ++r) ones[r] = (short)0x3F80;   // bf16 1.0

    auto stage = [&](int T, int parity) {
        const ushort_t* Vs = Vb + (size_t)T * 64;
        char* dst = sbase + parity * 8192;
#pragma unroll
        for (int iss = 0; iss < 2; ++iss)
            gload_lds16(Vs + vOff[iss], dst + dstL[iss]);
    };

    stage(hs * 16, 0);
    __syncthreads();

    char* mybase = lds + h2 * 16384;
    for (int t = 0; t < 16; ++t) {
        char* cb = mybase + (t & 1) * 8192;
        if (t < 15) stage(hs * 16 + t + 1, (t + 1) & 1);

        int kvi = h2 * 16 + t;
        unsigned long long w0 = pmq[(size_t)kvi * 2048];
        unsigned long long w1 = pmq[(size_t)kvi * 2048 + 16];
        const ushort_t* Kt = Kw + (size_t)kvi * 4096;

        f32x4 sc[2][4];
        __builtin_amdgcn_s_setprio(1);
#pragma unroll
        for (int nf = 0; nf < 4; ++nf) {
            const ushort_t* Krow = Kt + nf * 1024;     // (nf*16 rows) * 64 d
            short8 k0 = *(const short8*)(Krow);
            short8 k1 = *(const short8*)(Krow + 32);
#pragma unroll
            for (int qf = 0; qf < 2; ++qf) {
                f32x4 s = mfma32(k0, qreg[qf][0], (f32x4)0.0f);
                sc[qf][nf] = mfma32(k1, qreg[qf][1], s);
            }
        }
        __builtin_amdgcn_s_setprio(0);

        short4v pk[2][4];
#pragma unroll
        for (int qf = 0; qf < 2; ++qf) {
            unsigned long long ws = (qf == 0 ? w0 : w1) >> (gr * 4);
            uint32_t lo = (uint32_t)ws, hi = (uint32_t)(ws >> 32);
#pragma unroll
            for (int nf = 0; nf < 4; ++nf) {
                uint32_t wb = nf < 2 ? lo : hi;
                uint32_t u[4];
#pragma unroll
                for (int r = 0; r < 4; ++r) {
                    uint32_t bit = wb & (1u << ((nf & 1) * 16 + r));
                    float sel = bit ? sc[qf][nf][r] : -1.0e9f;
                    u[r] = fbits(fexp2(sel)) + 0x8000u;
                }
                union { uint32_t d[2]; short4v v; } pp;
                pp.d[0] = __builtin_amdgcn_perm(u[1], u[0], 0x07060302u);
                pp.d[1] = __builtin_amdgcn_perm(u[3], u[2], 0x07060302u);
                pk[qf][nf] = pp.v;
            }
        }

        __builtin_amdgcn_s_setprio(1);
#pragma unroll
        for (int nf = 0; nf < 4; ++nf) {
#pragma unroll
            for (int df = 0; df < 4; ++df) {
                short4v vf = *(const short4v*)(cb + aV[nf] + df * 2048);
                acc[0][df] = mfma16(pk[0][nf], vf, acc[0][df]);
                acc[1][df] = mfma16(pk[1][nf], vf, acc[1][df]);
            }
            accl[0] = mfma16(pk[0][nf], ones, accl[0]);
            accl[1] = mfma16(pk[1][nf], ones, accl[1]);
        }
        __builtin_amdgcn_s_setprio(0);
        __syncthreads();
    }

    // ---- merge kv-halves within each wave pair (exact: unnormalized partials add) ----
    if (h2) {
        float* dst = (float*)(lds + qg * 10240 + lane * 160);
#pragma unroll
        for (int qf = 0; qf < 2; ++qf) {
#pragma unroll
            for (int df = 0; df < 4; ++df)
                *(f32x4*)(dst + qf * 16 + df * 4) = acc[qf][df];
            *(f32x4*)(dst + 32 + qf * 4) = accl[qf];
        }
    }
    __syncthreads();
    if (!h2) {
        const float* src = (const float*)(lds + qg * 10240 + lane * 160);
#pragma unroll
        for (int qf = 0; qf < 2; ++qf) {
#pragma unroll
            for (int df = 0; df < 4; ++df)
                acc[qf][df] += *(const f32x4*)(src + qf * 16 + df * 4);
            accl[qf] += *(const f32x4*)(src + 32 + qf * 4);
        }
#pragma unroll
        for (int qf = 0; qf < 2; ++qf) {
            float inv[4];
#pragma unroll
            for (int r = 0; r < 4; ++r) inv[r] = 1.0f / accl[qf][r];
#pragma unroll
            for (int df = 0; df < 4; ++df)
#pragma unroll
                for (int r = 0; r < 4; ++r) {
                    int q = q0w + qf * 16 + gr * 4 + r;
                    int d = df * 16 + cl;
                    ctx[((size_t)b * S + q) * 1024 + h * 64 + d] = f2bf(acc[qf][df][r] * inv[r]);
                }
        }
    }
}

// ---------------- launch ----------------
extern "C" void kernel_launch(void* const* d_in, const int* in_sizes, int n_in,
                              void* d_out, int out_size, void* d_ws, size_t ws_size,
                              hipStream_t stream) {
    const float* query = (const float*)d_in[0];
    const float* key   = (const float*)d_in[1];
    const float* value = (const float*)d_in[2];
    const int*   mask  = (const int*)d_in[3];
    const float* w_q = (const float*)d_in[4];
    const float* b_q = (const float*)d_in[5];
    const float* w_k = (const float*)d_in[6];
    const float* b_k = (const float*)d_in[7];
    const float* w_v = (const float*)d_in[8];
    const float* b_v = (const float*)d_in[9];
    const float* w_o = (const float*)d_in[10];
    const float* b_o = (const float*)d_in[11];

    char* ws = (char*)d_ws;
    const size_t MB = 1 << 20;
    ushort_t* xq  = (ushort_t*)(ws + 0 * MB);
    ushort_t* xk  = (ushort_t*)(ws + 8 * MB);
    ushort_t* xv  = (ushort_t*)(ws + 16 * MB);
    ushort_t* wq  = (ushort_t*)(ws + 24 * MB);
    ushort_t* wk  = (ushort_t*)(ws + 26 * MB);
    ushort_t* wv  = (ushort_t*)(ws + 28 * MB);
    ushort_t* wo  = (ushort_t*)(ws + 30 * MB);
    ushort_t* qhm = (ushort_t*)(ws + 32 * MB);
    ushort_t* khm = (ushort_t*)(ws + 40 * MB);
    ushort_t* vt  = (ushort_t*)(ws + 48 * MB);
    unsigned long long* pm = (unsigned long long*)(ws + 56 * MB);
    ushort_t* ctx = (ushort_t*)(ws + 0 * MB);   // alias xq (dead after QKV gemm)

    // fold 1/sqrt(D_K)=0.125 AND log2(e) into Q so softmax is a bare v_exp_f32
    const float QSCALE = 0.125f * 1.44269504088896f;

    cvt_all<<<dim3(1024, 7), 256, 0, stream>>>(query, key, value, w_q, w_k, w_v, w_o,
                                               xq, xk, xv, wq, wk, wv, wo);
    pack_mask<<<32768, 256, 0, stream>>>(mask, pm);

    gemm3<2><<<dim3(8, 64, 3), 256, 0, stream>>>(xq, xk, xv, wq, wk, wv, b_q, b_k, b_v,
                                                 qhm, khm, vt, -1, QSCALE);

    attn<<<512, 512, 0, stream>>>(qhm, khm, vt, pm, ctx);

    gemm3<2><<<dim3(8, 64, 1), 256, 0, stream>>>(ctx, ctx, ctx, wo, wo, wo, b_o, b_o, b_o,
                                                 d_out, d_out, d_out, 2, 1.0f);
}

// Round 12
// 142.314 us; speedup vs baseline: 2.4850x; 2.4850x over previous
//
#include <hip/hip_runtime.h>
#include <hip/hip_bf16.h>
#include <stdint.h>

typedef __attribute__((ext_vector_type(8))) short short8;   // 8 bf16 (x32 mfma A/B)
typedef __attribute__((ext_vector_type(4))) short short4v;  // 4 bf16 (x16 mfma A/B)
typedef __attribute__((ext_vector_type(4))) float f32x4;
typedef __attribute__((ext_vector_type(4))) unsigned short us4;
typedef unsigned short ushort_t;

#define LDS_AS __attribute__((address_space(3)))
#define GLB_AS __attribute__((address_space(1)))

__device__ __forceinline__ void gload_lds16(const void* g, void* l) {
    __builtin_amdgcn_global_load_lds((const GLB_AS uint32_t*)g, (LDS_AS uint32_t*)l, 16, 0, 0);
}

__device__ __forceinline__ unsigned short f2bf(float f) {
    union { float f; uint32_t u; } v; v.f = f;
    uint32_t r = v.u + 0x7FFFu + ((v.u >> 16) & 1u);   // RNE
    return (unsigned short)(r >> 16);
}

__device__ __forceinline__ float fexp2(float x) {
#if __has_builtin(__builtin_amdgcn_exp2f)
    return __builtin_amdgcn_exp2f(x);
#else
    return exp2f(x);
#endif
}

__device__ __forceinline__ uint32_t fbits(float f) {
    union { float f; uint32_t u; } v; v.f = f; return v.u;
}

__device__ __forceinline__ f32x4 mfma32(short8 a, short8 b, f32x4 c) {
    return __builtin_amdgcn_mfma_f32_16x16x32_bf16(a, b, c, 0, 0, 0);
}
__device__ __forceinline__ f32x4 mfma16(short4v a, short4v b, f32x4 c) {
    return __builtin_amdgcn_mfma_f32_16x16x16bf16_1k(a, b, c, 0, 0, 0);
}

// read one MFMA frag (16B) from an XOR-swizzled [rows][64 bf16] LDS tile
__device__ __forceinline__ short8 lds_frag(const char* base, int row, int kc) {
    int byte = row * 128 + ((kc ^ (row & 7)) << 4);
    return *(const short8*)(base + byte);
}

// ---------------- fused fp32 -> bf16 conversion (7 tensors, one launch) ----------------
__global__ __launch_bounds__(256) void cvt_all(
    const float* p0, const float* p1, const float* p2, const float* p3,
    const float* p4, const float* p5, const float* p6,
    ushort_t* o0, ushort_t* o1, ushort_t* o2, ushort_t* o3,
    ushort_t* o4, ushort_t* o5, ushort_t* o6) {
    int z = blockIdx.y;
    const float* in = z == 0 ? p0 : z == 1 ? p1 : z == 2 ? p2 : z == 3 ? p3 : z == 4 ? p4 : z == 5 ? p5 : p6;
    ushort_t* out = z == 0 ? o0 : z == 1 ? o1 : z == 2 ? o2 : z == 3 ? o3 : z == 4 ? o4 : z == 5 ? o5 : o6;
    int n4 = z < 3 ? 1048576 : 262144;
    int i = blockIdx.x * 256 + threadIdx.x;
    int stride = gridDim.x * 256;
    for (; i < n4; i += stride) {
        float4 f = ((const float4*)in)[i];
        us4 o;
        o[0] = f2bf(f.x); o[1] = f2bf(f.y); o[2] = f2bf(f.z); o[3] = f2bf(f.w);
        ((us4*)out)[i] = o;
    }
}

// ---------------- mask bit-packing, transposed layout [b][kvblk(32)][q(2048)] ----------------
__global__ __launch_bounds__(256) void pack_mask(const int* __restrict__ mask,
                                                 unsigned long long* __restrict__ out) {
    int i = blockIdx.x * 256 + threadIdx.x;          // bit index over [b][q][k]
    unsigned long long bits = __ballot(mask[i] != 0);
    if ((threadIdx.x & 63) == 0) {
        int k = i & 2047, q = (i >> 11) & 2047, b = i >> 22;
        out[((size_t)b * 32 + (k >> 6)) * 2048 + q] = bits;
    }
}

// ---------------- GEMM core: (MI*32)x128 tile, K=1024, double-buffered prefetch ----------
// Issue stage(kt+1) BEFORE compute(kt); one barrier per iter. No setprio here: barrier-
// locked GEMM waves gain nothing from priority (m190 regime).
template<int MI>
__device__ __forceinline__ void gemm_core(const ushort_t* Ab, const ushort_t* Wb,
                                          char* lds, int tid, f32x4 acc[MI][4]) {
    constexpr int K = 1024;
    constexpr int ABYTES = MI * 4096;          // A tile: MI*32 rows x 128B
    constexpr int TILE = ABYTES + 16384;       // + B tile (128 rows x 128B)
    int lane = tid & 63, wid = tid >> 6;
    int cl = lane & 15, gr = lane >> 4;
    int wm = (wid >> 1) * (MI * 16), wn = (wid & 1) * 64;
#pragma unroll
    for (int i = 0; i < MI; ++i)
#pragma unroll
        for (int j = 0; j < 4; ++j) acc[i][j] = (f32x4)0.0f;

    // hoisted per-thread staging offsets (only k0 varies per iter)
    int aOff[MI], aDst[MI], bOff[4], bDst[4];
#pragma unroll
    for (int iss = 0; iss < MI; ++iss) {
        int c = iss * 256 + tid;
        int r = c >> 3, kc = (c & 7) ^ (r & 7);
        aOff[iss] = r * K + kc * 8;
        aDst[iss] = c * 16;
    }
#pragma unroll
    for (int iss = 0; iss < 4; ++iss) {
        int c = iss * 256 + tid;
        int r = c >> 3, kc = (c & 7) ^ (r & 7);
        bOff[iss] = r * K + kc * 8;
        bDst[iss] = c * 16;
    }

    auto stage = [&](int kt, char* dst) {
        int k0 = kt * 64;
#pragma unroll
        for (int iss = 0; iss < MI; ++iss)
            gload_lds16(Ab + aOff[iss] + k0, dst + aDst[iss]);
#pragma unroll
        for (int iss = 0; iss < 4; ++iss)
            gload_lds16(Wb + bOff[iss] + k0, dst + ABYTES + bDst[iss]);
    };

    stage(0, lds);
    __syncthreads();

    for (int kt = 0; kt < K / 64; ++kt) {
        char* cb = lds + (kt & 1) * TILE;
        if (kt < K / 64 - 1) stage(kt + 1, lds + ((kt + 1) & 1) * TILE);
        char* cA = cb;
        char* cW = cb + ABYTES;
#pragma unroll
        for (int ks = 0; ks < 2; ++ks) {
            short8 af[MI], wf[4];
#pragma unroll
            for (int t = 0; t < MI; ++t)
                af[t] = lds_frag(cA, wm + t * 16 + cl, ks * 4 + gr);
#pragma unroll
            for (int t = 0; t < 4; ++t)
                wf[t] = lds_frag(cW, wn + t * 16 + cl, ks * 4 + gr);
#pragma unroll
            for (int i = 0; i < MI; ++i)
#pragma unroll
                for (int j = 0; j < 4; ++j)
                    acc[i][j] = mfma32(af[i], wf[j], acc[i][j]);
        }
        __syncthreads();   // drains prefetch (already landed under compute) + guards buf reuse
    }
}

// mode 0: bf16 out head-major [b,h,s,d]; mode 1: bf16 out [b,h,d,s]; mode 2: fp32 row-major
// Tile: (MI*32)x128. Grid (8, M/(MI*32), z). Bijective XCD swizzle over the flat block id.
template<int MI>
__global__ __launch_bounds__(256, 3)
void gemm3(const ushort_t* A0, const ushort_t* A1, const ushort_t* A2,
           const ushort_t* W0, const ushort_t* W1, const ushort_t* W2,
           const float* B0, const float* B1, const float* B2,
           void* O0, void* O1, void* O2, int mode_ovr, float scl0) {
    __shared__ char lds[2 * (MI * 4096 + 16384)];

    // XCD swizzle: consecutive logical ids land on one XCD; bx fastest (shared A panel)
    int gx = gridDim.x, gy = gridDim.y;
    int nwg = gx * gy * gridDim.z;
    int bid = blockIdx.x + gx * (blockIdx.y + gy * blockIdx.z);
    int nb = (bid & 7) * (nwg >> 3) + (bid >> 3);
    int bx = nb % gx;
    int t2 = nb / gx;
    int by = t2 % gy;
    int z = t2 / gy;

    const ushort_t* A = z == 0 ? A0 : z == 1 ? A1 : A2;
    const ushort_t* W = z == 0 ? W0 : z == 1 ? W1 : W2;
    const float* bias = z == 0 ? B0 : z == 1 ? B1 : B2;
    void* out = z == 0 ? O0 : z == 1 ? O1 : O2;
    int mode = mode_ovr >= 0 ? mode_ovr : (z == 2 ? 1 : 0);
    float scl = z == 0 ? scl0 : 1.0f;

    int tid = threadIdx.x, lane = tid & 63, wid = tid >> 6;
    int cl = lane & 15, gr = lane >> 4;
    int wm = (wid >> 1) * (MI * 16), wn = (wid & 1) * 64;
    int bm = by * (MI * 32), bn = bx * 128;

    f32x4 acc[MI][4];
    gemm_core<MI>(A + (size_t)bm * 1024, W + (size_t)bn * 1024, lds, tid, acc);

#pragma unroll
    for (int j = 0; j < 4; ++j) {
        int n = bn + wn + j * 16 + cl;
        float bv = bias[n];
#pragma unroll
        for (int i = 0; i < MI; ++i) {
            int mbase = bm + wm + i * 16 + gr * 4;
            if (mode == 0) {
#pragma unroll
                for (int r = 0; r < 4; ++r) {
                    int m = mbase + r;
                    float v = (acc[i][j][r] + bv) * scl;
                    size_t idx = (((size_t)((m >> 11) * 16 + (n >> 6))) * 2048 + (m & 2047)) * 64 + (n & 63);
                    ((ushort_t*)out)[idx] = f2bf(v);
                }
            } else if (mode == 1) {
                us4 pk;
#pragma unroll
                for (int r = 0; r < 4; ++r) pk[r] = f2bf(acc[i][j][r] + bv);
                size_t idx = (((size_t)((mbase >> 11) * 16 + (n >> 6))) * 64 + (n & 63)) * 2048 + (mbase & 2047);
                *(us4*)((ushort_t*)out + idx) = pk;
            } else {
#pragma unroll
                for (int r = 0; r < 4; ++r)
                    ((float*)out)[(size_t)(mbase + r) * 1024 + n] = acc[i][j][r] + bv;
            }
        }
    }
}

// ---------------- fused masked attention v8 (round-10 proven: 60.2 us) ----------------
// grid 512 = (b,h)*16 q-tiles of 128 rows; 8 waves = 4 q-groups x 2 kv-halves.
// K and V both staged in LDS (2 streams x 2 bufs x 16KB = 64KB); deferred softmax,
// in-register P, ones-column MFMA row-sums, setprio around MFMA clusters.
__global__ __launch_bounds__(512, 4)
void attn(const ushort_t* __restrict__ Q, const ushort_t* __restrict__ Kh,
          const ushort_t* __restrict__ Vt, const unsigned long long* __restrict__ PM,
          ushort_t* __restrict__ ctx) {
    constexpr int S = 2048;
    __shared__ char lds[65536];   // [2 streams][2 bufs][K 8KB | V 8KB]; reused for merge
    int tid = threadIdx.x, lane = tid & 63, wid = tid >> 6;
    int cl = lane & 15, gr = lane >> 4, c7 = cl & 7;
    int h2 = wid & 1;            // kv-half this wave computes
    int qg = wid >> 1;           // q-group 0..3

    int blk = (blockIdx.x & 7) * 64 + (blockIdx.x >> 3);
    int bh = blk >> 4, qt = blk & 15;
    int b = bh >> 4, h = bh & 15;
    const ushort_t* Qb = Q + (size_t)bh * S * 64;
    const ushort_t* Kb = Kh + (size_t)bh * S * 64;
    const ushort_t* Vb = Vt + (size_t)bh * 64 * S;
    int q0w = qt * 128 + qg * 32;

    short8 qreg[2][2];
#pragma unroll
    for (int qf = 0; qf < 2; ++qf)
#pragma unroll
        for (int ks = 0; ks < 2; ++ks)
            qreg[qf][ks] = *(const short8*)(Qb + (size_t)(q0w + qf * 16 + cl) * 64 + ks * 32 + gr * 8);

    f32x4 acc[2][4];
    f32x4 accl[2];
#pragma unroll
    for (int qf = 0; qf < 2; ++qf) {
        accl[qf] = (f32x4)0.0f;
#pragma unroll
        for (int df = 0; df < 4; ++df) acc[qf][df] = (f32x4)0.0f;
    }

    int hs = tid >> 8, stid = tid & 255;
    int kOff[2], vOff[2], dstL[2];
#pragma unroll
    for (int iss = 0; iss < 2; ++iss) {
        int L = iss * 256 + stid;
        int r = L >> 3, c = (L & 7) ^ (r & 7);
        kOff[iss] = r * 64 + c * 8;
        vOff[iss] = r * S + c * 8;
        dstL[iss] = L * 16;
    }
    char* sbase = lds + hs * 32768;

    int aK0 = cl * 128 + ((0 * 4 + gr) ^ c7) * 16;
    int aK1 = cl * 128 + ((1 * 4 + gr) ^ c7) * 16;
    int aV[4];
#pragma unroll
    for (int nf = 0; nf < 4; ++nf)
        aV[nf] = cl * 128 + (((2 * nf) + (gr >> 1)) ^ c7) * 16 + (gr & 1) * 8;

    const unsigned long long* pmq = PM + (size_t)b * 32 * 2048 + q0w + cl;

    short4v ones;
#pragma unroll
    for (int r = 0; r < 4; ++r) ones[r] = (short)0x3F80;   // bf16 1.0

    auto stage = [&](int T, int parity) {
        const ushort_t* Ks = Kb + (size_t)T * 4096;
        const ushort_t* Vs = Vb + (size_t)T * 64;
        char* dst = sbase + parity * 16384;
#pragma unroll
        for (int iss = 0; iss < 2; ++iss) {
            gload_lds16(Ks + kOff[iss], dst + dstL[iss]);
            gload_lds16(Vs + vOff[iss], dst + 8192 + dstL[iss]);
        }
    };

    stage(hs * 16, 0);
    __syncthreads();

    char* mybase = lds + h2 * 32768;
    for (int t = 0; t < 16; ++t) {
        char* cb = mybase + (t & 1) * 16384;
        if (t < 15) stage(hs * 16 + t + 1, (t + 1) & 1);

        int kvi = h2 * 16 + t;
        unsigned long long w0 = pmq[(size_t)kvi * 2048];
        unsigned long long w1 = pmq[(size_t)kvi * 2048 + 16];

        f32x4 sc[2][4];
        __builtin_amdgcn_s_setprio(1);
#pragma unroll
        for (int nf = 0; nf < 4; ++nf) {
            short8 k0 = *(const short8*)(cb + aK0 + nf * 2048);
            short8 k1 = *(const short8*)(cb + aK1 + nf * 2048);
#pragma unroll
            for (int qf = 0; qf < 2; ++qf) {
                f32x4 s = mfma32(k0, qreg[qf][0], (f32x4)0.0f);
                sc[qf][nf] = mfma32(k1, qreg[qf][1], s);
            }
        }
        __builtin_amdgcn_s_setprio(0);

        short4v pk[2][4];
#pragma unroll
        for (int qf = 0; qf < 2; ++qf) {
            unsigned long long ws = (qf == 0 ? w0 : w1) >> (gr * 4);
            uint32_t lo = (uint32_t)ws, hi = (uint32_t)(ws >> 32);
#pragma unroll
            for (int nf = 0; nf < 4; ++nf) {
                uint32_t wb = nf < 2 ? lo : hi;
                uint32_t u[4];
#pragma unroll
                for (int r = 0; r < 4; ++r) {
                    uint32_t bit = wb & (1u << ((nf & 1) * 16 + r));
                    float sel = bit ? sc[qf][nf][r] : -1.0e9f;
                    u[r] = fbits(fexp2(sel)) + 0x8000u;
                }
                union { uint32_t d[2]; short4v v; } pp;
                pp.d[0] = __builtin_amdgcn_perm(u[1], u[0], 0x07060302u);
                pp.d[1] = __builtin_amdgcn_perm(u[3], u[2], 0x07060302u);
                pk[qf][nf] = pp.v;
            }
        }

        __builtin_amdgcn_s_setprio(1);
#pragma unroll
        for (int nf = 0; nf < 4; ++nf) {
#pragma unroll
            for (int df = 0; df < 4; ++df) {
                short4v vf = *(const short4v*)(cb + 8192 + aV[nf] + df * 2048);
                acc[0][df] = mfma16(pk[0][nf], vf, acc[0][df]);
                acc[1][df] = mfma16(pk[1][nf], vf, acc[1][df]);
            }
            accl[0] = mfma16(pk[0][nf], ones, accl[0]);
            accl[1] = mfma16(pk[1][nf], ones, accl[1]);
        }
        __builtin_amdgcn_s_setprio(0);
        __syncthreads();
    }

    if (h2) {
        float* dst = (float*)(lds + qg * 10240 + lane * 160);
#pragma unroll
        for (int qf = 0; qf < 2; ++qf) {
#pragma unroll
            for (int df = 0; df < 4; ++df)
                *(f32x4*)(dst + qf * 16 + df * 4) = acc[qf][df];
            *(f32x4*)(dst + 32 + qf * 4) = accl[qf];
        }
    }
    __syncthreads();
    if (!h2) {
        const float* src = (const float*)(lds + qg * 10240 + lane * 160);
#pragma unroll
        for (int qf = 0; qf < 2; ++qf) {
#pragma unroll
            for (int df = 0; df < 4; ++df)
                acc[qf][df] += *(const f32x4*)(src + qf * 16 + df * 4);
            accl[qf] += *(const f32x4*)(src + 32 + qf * 4);
        }
#pragma unroll
        for (int qf = 0; qf < 2; ++qf) {
            float inv[4];
#pragma unroll
            for (int r = 0; r < 4; ++r) inv[r] = 1.0f / accl[qf][r];
#pragma unroll
            for (int df = 0; df < 4; ++df)
#pragma unroll
                for (int r = 0; r < 4; ++r) {
                    int q = q0w + qf * 16 + gr * 4 + r;
                    int d = df * 16 + cl;
                    ctx[((size_t)b * S + q) * 1024 + h * 64 + d] = f2bf(acc[qf][df][r] * inv[r]);
                }
        }
    }
}

// ---------------- launch ----------------
extern "C" void kernel_launch(void* const* d_in, const int* in_sizes, int n_in,
                              void* d_out, int out_size, void* d_ws, size_t ws_size,
                              hipStream_t stream) {
    const float* query = (const float*)d_in[0];
    const float* key   = (const float*)d_in[1];
    const float* value = (const float*)d_in[2];
    const int*   mask  = (const int*)d_in[3];
    const float* w_q = (const float*)d_in[4];
    const float* b_q = (const float*)d_in[5];
    const float* w_k = (const float*)d_in[6];
    const float* b_k = (const float*)d_in[7];
    const float* w_v = (const float*)d_in[8];
    const float* b_v = (const float*)d_in[9];
    const float* w_o = (const float*)d_in[10];
    const float* b_o = (const float*)d_in[11];

    char* ws = (char*)d_ws;
    const size_t MB = 1 << 20;
    ushort_t* xq  = (ushort_t*)(ws + 0 * MB);
    ushort_t* xk  = (ushort_t*)(ws + 8 * MB);
    ushort_t* xv  = (ushort_t*)(ws + 16 * MB);
    ushort_t* wq  = (ushort_t*)(ws + 24 * MB);
    ushort_t* wk  = (ushort_t*)(ws + 26 * MB);
    ushort_t* wv  = (ushort_t*)(ws + 28 * MB);
    ushort_t* wo  = (ushort_t*)(ws + 30 * MB);
    ushort_t* qhm = (ushort_t*)(ws + 32 * MB);
    ushort_t* khm = (ushort_t*)(ws + 40 * MB);
    ushort_t* vt  = (ushort_t*)(ws + 48 * MB);
    unsigned long long* pm = (unsigned long long*)(ws + 56 * MB);
    ushort_t* ctx = (ushort_t*)(ws + 0 * MB);   // alias xq (dead after QKV gemm)

    // fold 1/sqrt(D_K)=0.125 AND log2(e) into Q so softmax is a bare v_exp_f32
    const float QSCALE = 0.125f * 1.44269504088896f;

    cvt_all<<<dim3(1024, 7), 256, 0, stream>>>(query, key, value, w_q, w_k, w_v, w_o,
                                               xq, xk, xv, wq, wk, wv, wo);
    pack_mask<<<32768, 256, 0, stream>>>(mask, pm);

    gemm3<2><<<dim3(8, 64, 3), 256, 0, stream>>>(xq, xk, xv, wq, wk, wv, b_q, b_k, b_v,
                                                 qhm, khm, vt, -1, QSCALE);

    attn<<<512, 512, 0, stream>>>(qhm, khm, vt, pm, ctx);

    gemm3<2><<<dim3(8, 64, 1), 256, 0, stream>>>(ctx, ctx, ctx, wo, wo, wo, b_o, b_o, b_o,
                                                 d_out, d_out, d_out, 2, 1.0f);
}

// Round 13
// 139.579 us; speedup vs baseline: 2.5337x; 1.0196x over previous
//
#include <hip/hip_runtime.h>
#include <hip/hip_bf16.h>
#include <stdint.h>

typedef __attribute__((ext_vector_type(8))) short short8;   // 8 bf16 (x32 mfma A/B)
typedef __attribute__((ext_vector_type(4))) short short4v;  // 4 bf16 (x16 mfma A/B)
typedef __attribute__((ext_vector_type(4))) float f32x4;
typedef __attribute__((ext_vector_type(4))) unsigned short us4;
typedef unsigned short ushort_t;

#define LDS_AS __attribute__((address_space(3)))
#define GLB_AS __attribute__((address_space(1)))

__device__ __forceinline__ void gload_lds16(const void* g, void* l) {
    __builtin_amdgcn_global_load_lds((const GLB_AS uint32_t*)g, (LDS_AS uint32_t*)l, 16, 0, 0);
}

__device__ __forceinline__ unsigned short f2bf(float f) {
    union { float f; uint32_t u; } v; v.f = f;
    uint32_t r = v.u + 0x7FFFu + ((v.u >> 16) & 1u);   // RNE
    return (unsigned short)(r >> 16);
}

__device__ __forceinline__ float fexp2(float x) {
#if __has_builtin(__builtin_amdgcn_exp2f)
    return __builtin_amdgcn_exp2f(x);
#else
    return exp2f(x);
#endif
}

__device__ __forceinline__ uint32_t fbits(float f) {
    union { float f; uint32_t u; } v; v.f = f; return v.u;
}

__device__ __forceinline__ f32x4 mfma32(short8 a, short8 b, f32x4 c) {
    return __builtin_amdgcn_mfma_f32_16x16x32_bf16(a, b, c, 0, 0, 0);
}
__device__ __forceinline__ f32x4 mfma16(short4v a, short4v b, f32x4 c) {
    return __builtin_amdgcn_mfma_f32_16x16x16bf16_1k(a, b, c, 0, 0, 0);
}

// read one MFMA frag (16B) from an XOR-swizzled [rows][64 bf16] LDS tile
__device__ __forceinline__ short8 lds_frag(const char* base, int row, int kc) {
    int byte = row * 128 + ((kc ^ (row & 7)) << 4);
    return *(const short8*)(base + byte);
}

// ---------------- fused prep: fp32->bf16 (7 tensors) + mask bit-pack, one launch --------
// z<7: convert tensor z. z==7: pack mask [b][q][k] -> bits [b][kvblk(32)][q(2048)].
__global__ __launch_bounds__(256) void prep_all(
    const float* p0, const float* p1, const float* p2, const float* p3,
    const float* p4, const float* p5, const float* p6,
    ushort_t* o0, ushort_t* o1, ushort_t* o2, ushort_t* o3,
    ushort_t* o4, ushort_t* o5, ushort_t* o6,
    const int* __restrict__ mask, unsigned long long* __restrict__ pmout) {
    int z = blockIdx.y;
    if (z == 7) {
#pragma unroll 1
        for (int it = 0; it < 32; ++it) {
            int i = it * 262144 + blockIdx.x * 256 + threadIdx.x;   // bit index over [b][q][k]
            unsigned long long bits = __ballot(mask[i] != 0);
            if ((threadIdx.x & 63) == 0) {
                int k = i & 2047, q = (i >> 11) & 2047, b = i >> 22;
                pmout[((size_t)b * 32 + (k >> 6)) * 2048 + q] = bits;
            }
        }
        return;
    }
    const float* in = z == 0 ? p0 : z == 1 ? p1 : z == 2 ? p2 : z == 3 ? p3 : z == 4 ? p4 : z == 5 ? p5 : p6;
    ushort_t* out = z == 0 ? o0 : z == 1 ? o1 : z == 2 ? o2 : z == 3 ? o3 : z == 4 ? o4 : z == 5 ? o5 : o6;
    int n4 = z < 3 ? 1048576 : 262144;
    int i = blockIdx.x * 256 + threadIdx.x;
    int stride = gridDim.x * 256;
    for (; i < n4; i += stride) {
        float4 f = ((const float4*)in)[i];
        us4 o;
        o[0] = f2bf(f.x); o[1] = f2bf(f.y); o[2] = f2bf(f.z); o[3] = f2bf(f.w);
        ((us4*)out)[i] = o;
    }
}

// ---------------- GEMM core: (MI*32)x128 tile, K=1024, double-buffered prefetch ----------
// Issue stage(kt+1) BEFORE compute(kt); one barrier per iter. No setprio here: barrier-
// locked GEMM waves gain nothing from priority (m190 regime).
template<int MI>
__device__ __forceinline__ void gemm_core(const ushort_t* Ab, const ushort_t* Wb,
                                          char* lds, int tid, f32x4 acc[MI][4]) {
    constexpr int K = 1024;
    constexpr int ABYTES = MI * 4096;          // A tile: MI*32 rows x 128B
    constexpr int TILE = ABYTES + 16384;       // + B tile (128 rows x 128B)
    int lane = tid & 63, wid = tid >> 6;
    int cl = lane & 15, gr = lane >> 4;
    int wm = (wid >> 1) * (MI * 16), wn = (wid & 1) * 64;
#pragma unroll
    for (int i = 0; i < MI; ++i)
#pragma unroll
        for (int j = 0; j < 4; ++j) acc[i][j] = (f32x4)0.0f;

    // hoisted per-thread staging offsets (only k0 varies per iter)
    int aOff[MI], aDst[MI], bOff[4], bDst[4];
#pragma unroll
    for (int iss = 0; iss < MI; ++iss) {
        int c = iss * 256 + tid;
        int r = c >> 3, kc = (c & 7) ^ (r & 7);
        aOff[iss] = r * K + kc * 8;
        aDst[iss] = c * 16;
    }
#pragma unroll
    for (int iss = 0; iss < 4; ++iss) {
        int c = iss * 256 + tid;
        int r = c >> 3, kc = (c & 7) ^ (r & 7);
        bOff[iss] = r * K + kc * 8;
        bDst[iss] = c * 16;
    }

    auto stage = [&](int kt, char* dst) {
        int k0 = kt * 64;
#pragma unroll
        for (int iss = 0; iss < MI; ++iss)
            gload_lds16(Ab + aOff[iss] + k0, dst + aDst[iss]);
#pragma unroll
        for (int iss = 0; iss < 4; ++iss)
            gload_lds16(Wb + bOff[iss] + k0, dst + ABYTES + bDst[iss]);
    };

    stage(0, lds);
    __syncthreads();

    for (int kt = 0; kt < K / 64; ++kt) {
        char* cb = lds + (kt & 1) * TILE;
        if (kt < K / 64 - 1) stage(kt + 1, lds + ((kt + 1) & 1) * TILE);
        char* cA = cb;
        char* cW = cb + ABYTES;
#pragma unroll
        for (int ks = 0; ks < 2; ++ks) {
            short8 af[MI], wf[4];
#pragma unroll
            for (int t = 0; t < MI; ++t)
                af[t] = lds_frag(cA, wm + t * 16 + cl, ks * 4 + gr);
#pragma unroll
            for (int t = 0; t < 4; ++t)
                wf[t] = lds_frag(cW, wn + t * 16 + cl, ks * 4 + gr);
#pragma unroll
            for (int i = 0; i < MI; ++i)
#pragma unroll
                for (int j = 0; j < 4; ++j)
                    acc[i][j] = mfma32(af[i], wf[j], acc[i][j]);
        }
        __syncthreads();   // drains prefetch (already landed under compute) + guards buf reuse
    }
}

// mode 0: bf16 out head-major [b,h,s,d]; mode 1: bf16 out [b,h,d,s]; mode 2: fp32 row-major
// Tile: (MI*32)x128. Grid (8, M/(MI*32), z). Bijective XCD swizzle over the flat block id.
template<int MI>
__global__ __launch_bounds__(256, 3)
void gemm3(const ushort_t* A0, const ushort_t* A1, const ushort_t* A2,
           const ushort_t* W0, const ushort_t* W1, const ushort_t* W2,
           const float* B0, const float* B1, const float* B2,
           void* O0, void* O1, void* O2, int mode_ovr, float scl0) {
    __shared__ char lds[2 * (MI * 4096 + 16384)];

    // XCD swizzle: consecutive logical ids land on one XCD; bx fastest (shared A panel)
    int gx = gridDim.x, gy = gridDim.y;
    int nwg = gx * gy * gridDim.z;
    int bid = blockIdx.x + gx * (blockIdx.y + gy * blockIdx.z);
    int nb = (bid & 7) * (nwg >> 3) + (bid >> 3);
    int bx = nb % gx;
    int t2 = nb / gx;
    int by = t2 % gy;
    int z = t2 / gy;

    const ushort_t* A = z == 0 ? A0 : z == 1 ? A1 : A2;
    const ushort_t* W = z == 0 ? W0 : z == 1 ? W1 : W2;
    const float* bias = z == 0 ? B0 : z == 1 ? B1 : B2;
    void* out = z == 0 ? O0 : z == 1 ? O1 : O2;
    int mode = mode_ovr >= 0 ? mode_ovr : (z == 2 ? 1 : 0);
    float scl = z == 0 ? scl0 : 1.0f;

    int tid = threadIdx.x, lane = tid & 63, wid = tid >> 6;
    int cl = lane & 15, gr = lane >> 4;
    int wm = (wid >> 1) * (MI * 16), wn = (wid & 1) * 64;
    int bm = by * (MI * 32), bn = bx * 128;

    f32x4 acc[MI][4];
    gemm_core<MI>(A + (size_t)bm * 1024, W + (size_t)bn * 1024, lds, tid, acc);

#pragma unroll
    for (int j = 0; j < 4; ++j) {
        int n = bn + wn + j * 16 + cl;
        float bv = bias[n];
#pragma unroll
        for (int i = 0; i < MI; ++i) {
            int mbase = bm + wm + i * 16 + gr * 4;
            if (mode == 0) {
#pragma unroll
                for (int r = 0; r < 4; ++r) {
                    int m = mbase + r;
                    float v = (acc[i][j][r] + bv) * scl;
                    size_t idx = (((size_t)((m >> 11) * 16 + (n >> 6))) * 2048 + (m & 2047)) * 64 + (n & 63);
                    ((ushort_t*)out)[idx] = f2bf(v);
                }
            } else if (mode == 1) {
                us4 pk;
#pragma unroll
                for (int r = 0; r < 4; ++r) pk[r] = f2bf(acc[i][j][r] + bv);
                size_t idx = (((size_t)((mbase >> 11) * 16 + (n >> 6))) * 64 + (n & 63)) * 2048 + (mbase & 2047);
                *(us4*)((ushort_t*)out + idx) = pk;
            } else {
#pragma unroll
                for (int r = 0; r < 4; ++r)
                    ((float*)out)[(size_t)(mbase + r) * 1024 + n] = acc[i][j][r] + bv;
            }
        }
    }
}

// ---------------- fused masked attention v8b (v8 + truncation bf16 pack) ----------------
// grid 512 = (b,h)*16 q-tiles of 128 rows; 8 waves = 4 q-groups x 2 kv-halves.
// K and V both staged in LDS (2 streams x 2 bufs x 16KB = 64KB); deferred softmax,
// in-register P, ones-column MFMA row-sums, setprio around MFMA clusters.
// P pack is TRUNCATION (no +0x8000): numerator and denominator use the same pk, so
// the truncation bias cancels to first order in P.V/l.
__global__ __launch_bounds__(512, 4)
void attn(const ushort_t* __restrict__ Q, const ushort_t* __restrict__ Kh,
          const ushort_t* __restrict__ Vt, const unsigned long long* __restrict__ PM,
          ushort_t* __restrict__ ctx) {
    constexpr int S = 2048;
    __shared__ char lds[65536];   // [2 streams][2 bufs][K 8KB | V 8KB]; reused for merge
    int tid = threadIdx.x, lane = tid & 63, wid = tid >> 6;
    int cl = lane & 15, gr = lane >> 4, c7 = cl & 7;
    int h2 = wid & 1;            // kv-half this wave computes
    int qg = wid >> 1;           // q-group 0..3

    int blk = (blockIdx.x & 7) * 64 + (blockIdx.x >> 3);
    int bh = blk >> 4, qt = blk & 15;
    int b = bh >> 4, h = bh & 15;
    const ushort_t* Qb = Q + (size_t)bh * S * 64;
    const ushort_t* Kb = Kh + (size_t)bh * S * 64;
    const ushort_t* Vb = Vt + (size_t)bh * 64 * S;
    int q0w = qt * 128 + qg * 32;

    short8 qreg[2][2];
#pragma unroll
    for (int qf = 0; qf < 2; ++qf)
#pragma unroll
        for (int ks = 0; ks < 2; ++ks)
            qreg[qf][ks] = *(const short8*)(Qb + (size_t)(q0w + qf * 16 + cl) * 64 + ks * 32 + gr * 8);

    f32x4 acc[2][4];
    f32x4 accl[2];
#pragma unroll
    for (int qf = 0; qf < 2; ++qf) {
        accl[qf] = (f32x4)0.0f;
#pragma unroll
        for (int df = 0; df < 4; ++df) acc[qf][df] = (f32x4)0.0f;
    }

    int hs = tid >> 8, stid = tid & 255;
    int kOff[2], vOff[2], dstL[2];
#pragma unroll
    for (int iss = 0; iss < 2; ++iss) {
        int L = iss * 256 + stid;
        int r = L >> 3, c = (L & 7) ^ (r & 7);
        kOff[iss] = r * 64 + c * 8;
        vOff[iss] = r * S + c * 8;
        dstL[iss] = L * 16;
    }
    char* sbase = lds + hs * 32768;

    int aK0 = cl * 128 + ((0 * 4 + gr) ^ c7) * 16;
    int aK1 = cl * 128 + ((1 * 4 + gr) ^ c7) * 16;
    int aV[4];
#pragma unroll
    for (int nf = 0; nf < 4; ++nf)
        aV[nf] = cl * 128 + (((2 * nf) + (gr >> 1)) ^ c7) * 16 + (gr & 1) * 8;

    const unsigned long long* pmq = PM + (size_t)b * 32 * 2048 + q0w + cl;

    short4v ones;
#pragma unroll
    for (int r = 0; r < 4; ++r) ones[r] = (short)0x3F80;   // bf16 1.0

    auto stage = [&](int T, int parity) {
        const ushort_t* Ks = Kb + (size_t)T * 4096;
        const ushort_t* Vs = Vb + (size_t)T * 64;
        char* dst = sbase + parity * 16384;
#pragma unroll
        for (int iss = 0; iss < 2; ++iss) {
            gload_lds16(Ks + kOff[iss], dst + dstL[iss]);
            gload_lds16(Vs + vOff[iss], dst + 8192 + dstL[iss]);
        }
    };

    stage(hs * 16, 0);
    __syncthreads();

    char* mybase = lds + h2 * 32768;
    for (int t = 0; t < 16; ++t) {
        char* cb = mybase + (t & 1) * 16384;
        if (t < 15) stage(hs * 16 + t + 1, (t + 1) & 1);

        int kvi = h2 * 16 + t;
        unsigned long long w0 = pmq[(size_t)kvi * 2048];
        unsigned long long w1 = pmq[(size_t)kvi * 2048 + 16];

        f32x4 sc[2][4];
        __builtin_amdgcn_s_setprio(1);
#pragma unroll
        for (int nf = 0; nf < 4; ++nf) {
            short8 k0 = *(const short8*)(cb + aK0 + nf * 2048);
            short8 k1 = *(const short8*)(cb + aK1 + nf * 2048);
#pragma unroll
            for (int qf = 0; qf < 2; ++qf) {
                f32x4 s = mfma32(k0, qreg[qf][0], (f32x4)0.0f);
                sc[qf][nf] = mfma32(k1, qreg[qf][1], s);
            }
        }
        __builtin_amdgcn_s_setprio(0);

        short4v pk[2][4];
#pragma unroll
        for (int qf = 0; qf < 2; ++qf) {
            unsigned long long ws = (qf == 0 ? w0 : w1) >> (gr * 4);
            uint32_t lo = (uint32_t)ws, hi = (uint32_t)(ws >> 32);
#pragma unroll
            for (int nf = 0; nf < 4; ++nf) {
                uint32_t wb = nf < 2 ? lo : hi;
                uint32_t u[4];
#pragma unroll
                for (int r = 0; r < 4; ++r) {
                    uint32_t bit = wb & (1u << ((nf & 1) * 16 + r));
                    float sel = bit ? sc[qf][nf][r] : -1.0e9f;
                    u[r] = fbits(fexp2(sel));          // truncation pack (no +0x8000)
                }
                union { uint32_t d[2]; short4v v; } pp;
                pp.d[0] = __builtin_amdgcn_perm(u[1], u[0], 0x07060302u);
                pp.d[1] = __builtin_amdgcn_perm(u[3], u[2], 0x07060302u);
                pk[qf][nf] = pp.v;
            }
        }

        __builtin_amdgcn_s_setprio(1);
#pragma unroll
        for (int nf = 0; nf < 4; ++nf) {
#pragma unroll
            for (int df = 0; df < 4; ++df) {
                short4v vf = *(const short4v*)(cb + 8192 + aV[nf] + df * 2048);
                acc[0][df] = mfma16(pk[0][nf], vf, acc[0][df]);
                acc[1][df] = mfma16(pk[1][nf], vf, acc[1][df]);
            }
            accl[0] = mfma16(pk[0][nf], ones, accl[0]);
            accl[1] = mfma16(pk[1][nf], ones, accl[1]);
        }
        __builtin_amdgcn_s_setprio(0);
        __syncthreads();
    }

    if (h2) {
        float* dst = (float*)(lds + qg * 10240 + lane * 160);
#pragma unroll
        for (int qf = 0; qf < 2; ++qf) {
#pragma unroll
            for (int df = 0; df < 4; ++df)
                *(f32x4*)(dst + qf * 16 + df * 4) = acc[qf][df];
            *(f32x4*)(dst + 32 + qf * 4) = accl[qf];
        }
    }
    __syncthreads();
    if (!h2) {
        const float* src = (const float*)(lds + qg * 10240 + lane * 160);
#pragma unroll
        for (int qf = 0; qf < 2; ++qf) {
#pragma unroll
            for (int df = 0; df < 4; ++df)
                acc[qf][df] += *(const f32x4*)(src + qf * 16 + df * 4);
            accl[qf] += *(const f32x4*)(src + 32 + qf * 4);
        }
#pragma unroll
        for (int qf = 0; qf < 2; ++qf) {
            float inv[4];
#pragma unroll
            for (int r = 0; r < 4; ++r) inv[r] = 1.0f / accl[qf][r];
#pragma unroll
            for (int df = 0; df < 4; ++df)
#pragma unroll
                for (int r = 0; r < 4; ++r) {
                    int q = q0w + qf * 16 + gr * 4 + r;
                    int d = df * 16 + cl;
                    ctx[((size_t)b * S + q) * 1024 + h * 64 + d] = f2bf(acc[qf][df][r] * inv[r]);
                }
        }
    }
}

// ---------------- launch ----------------
extern "C" void kernel_launch(void* const* d_in, const int* in_sizes, int n_in,
                              void* d_out, int out_size, void* d_ws, size_t ws_size,
                              hipStream_t stream) {
    const float* query = (const float*)d_in[0];
    const float* key   = (const float*)d_in[1];
    const float* value = (const float*)d_in[2];
    const int*   mask  = (const int*)d_in[3];
    const float* w_q = (const float*)d_in[4];
    const float* b_q = (const float*)d_in[5];
    const float* w_k = (const float*)d_in[6];
    const float* b_k = (const float*)d_in[7];
    const float* w_v = (const float*)d_in[8];
    const float* b_v = (const float*)d_in[9];
    const float* w_o = (const float*)d_in[10];
    const float* b_o = (const float*)d_in[11];

    char* ws = (char*)d_ws;
    const size_t MB = 1 << 20;
    ushort_t* xq  = (ushort_t*)(ws + 0 * MB);
    ushort_t* xk  = (ushort_t*)(ws + 8 * MB);
    ushort_t* xv  = (ushort_t*)(ws + 16 * MB);
    ushort_t* wq  = (ushort_t*)(ws + 24 * MB);
    ushort_t* wk  = (ushort_t*)(ws + 26 * MB);
    ushort_t* wv  = (ushort_t*)(ws + 28 * MB);
    ushort_t* wo  = (ushort_t*)(ws + 30 * MB);
    ushort_t* qhm = (ushort_t*)(ws + 32 * MB);
    ushort_t* khm = (ushort_t*)(ws + 40 * MB);
    ushort_t* vt  = (ushort_t*)(ws + 48 * MB);
    unsigned long long* pm = (unsigned long long*)(ws + 56 * MB);
    ushort_t* ctx = (ushort_t*)(ws + 0 * MB);   // alias xq (dead after QKV gemm)

    // fold 1/sqrt(D_K)=0.125 AND log2(e) into Q so softmax is a bare v_exp_f32
    const float QSCALE = 0.125f * 1.44269504088896f;

    prep_all<<<dim3(1024, 8), 256, 0, stream>>>(query, key, value, w_q, w_k, w_v, w_o,
                                                xq, xk, xv, wq, wk, wv, wo, mask, pm);

    gemm3<2><<<dim3(8, 64, 3), 256, 0, stream>>>(xq, xk, xv, wq, wk, wv, b_q, b_k, b_v,
                                                 qhm, khm, vt, -1, QSCALE);

    attn<<<512, 512, 0, stream>>>(qhm, khm, vt, pm, ctx);

    gemm3<2><<<dim3(8, 64, 1), 256, 0, stream>>>(ctx, ctx, ctx, wo, wo, wo, b_o, b_o, b_o,
                                                 d_out, d_out, d_out, 2, 1.0f);
}

// Round 14
// 136.886 us; speedup vs baseline: 2.5836x; 1.0197x over previous
//
#include <hip/hip_runtime.h>
#include <hip/hip_bf16.h>
#include <stdint.h>

typedef __attribute__((ext_vector_type(8))) short short8;   // 8 bf16 (x32 mfma A/B)
typedef __attribute__((ext_vector_type(4))) short short4v;  // 4 bf16 (x16 mfma A/B)
typedef __attribute__((ext_vector_type(4))) float f32x4;
typedef __attribute__((ext_vector_type(4))) unsigned short us4;
typedef unsigned short ushort_t;

#define LDS_AS __attribute__((address_space(3)))
#define GLB_AS __attribute__((address_space(1)))

__device__ __forceinline__ void gload_lds16(const void* g, void* l) {
    __builtin_amdgcn_global_load_lds((const GLB_AS uint32_t*)g, (LDS_AS uint32_t*)l, 16, 0, 0);
}

__device__ __forceinline__ unsigned short f2bf(float f) {
    union { float f; uint32_t u; } v; v.f = f;
    uint32_t r = v.u + 0x7FFFu + ((v.u >> 16) & 1u);   // RNE
    return (unsigned short)(r >> 16);
}

__device__ __forceinline__ float fexp2(float x) {
#if __has_builtin(__builtin_amdgcn_exp2f)
    return __builtin_amdgcn_exp2f(x);
#else
    return exp2f(x);
#endif
}

__device__ __forceinline__ uint32_t fbits(float f) {
    union { float f; uint32_t u; } v; v.f = f; return v.u;
}

__device__ __forceinline__ f32x4 mfma32(short8 a, short8 b, f32x4 c) {
    return __builtin_amdgcn_mfma_f32_16x16x32_bf16(a, b, c, 0, 0, 0);
}
__device__ __forceinline__ f32x4 mfma16(short4v a, short4v b, f32x4 c) {
    return __builtin_amdgcn_mfma_f32_16x16x16bf16_1k(a, b, c, 0, 0, 0);
}

// read one MFMA frag (16B) from an XOR-swizzled [rows][64 bf16] LDS tile
__device__ __forceinline__ short8 lds_frag(const char* base, int row, int kc) {
    int byte = row * 128 + ((kc ^ (row & 7)) << 4);
    return *(const short8*)(base + byte);
}

// ---------------- fused prep: fp32->bf16 (7 tensors) + mask bit-pack, one launch --------
// z<7: convert tensor z. z==7: pack mask [b][q][k] -> bits [b][kvblk(32)][q(2048)].
__global__ __launch_bounds__(256) void prep_all(
    const float* p0, const float* p1, const float* p2, const float* p3,
    const float* p4, const float* p5, const float* p6,
    ushort_t* o0, ushort_t* o1, ushort_t* o2, ushort_t* o3,
    ushort_t* o4, ushort_t* o5, ushort_t* o6,
    const int* __restrict__ mask, unsigned long long* __restrict__ pmout) {
    int z = blockIdx.y;
    if (z == 7) {
#pragma unroll 1
        for (int it = 0; it < 32; ++it) {
            int i = it * 262144 + blockIdx.x * 256 + threadIdx.x;   // bit index over [b][q][k]
            unsigned long long bits = __ballot(mask[i] != 0);
            if ((threadIdx.x & 63) == 0) {
                int k = i & 2047, q = (i >> 11) & 2047, b = i >> 22;
                pmout[((size_t)b * 32 + (k >> 6)) * 2048 + q] = bits;
            }
        }
        return;
    }
    const float* in = z == 0 ? p0 : z == 1 ? p1 : z == 2 ? p2 : z == 3 ? p3 : z == 4 ? p4 : z == 5 ? p5 : p6;
    ushort_t* out = z == 0 ? o0 : z == 1 ? o1 : z == 2 ? o2 : z == 3 ? o3 : z == 4 ? o4 : z == 5 ? o5 : o6;
    int n4 = z < 3 ? 1048576 : 262144;
    int i = blockIdx.x * 256 + threadIdx.x;
    int stride = gridDim.x * 256;
    for (; i < n4; i += stride) {
        float4 f = ((const float4*)in)[i];
        us4 o;
        o[0] = f2bf(f.x); o[1] = f2bf(f.y); o[2] = f2bf(f.z); o[3] = f2bf(f.w);
        ((us4*)out)[i] = o;
    }
}

// ---------------- GEMM core: (MI*32)x128 tile, K=1024 ----------
// DBUF=1: double-buffered prefetch (issue stage(kt+1) before compute(kt), 1 barrier/iter).
// DBUF=0: m97-style single buffer (stage -> barrier -> compute -> barrier); relies on
//         3 blocks/CU implicit wave overlap (m114) to hide the drain.
template<int MI, int DBUF>
__device__ __forceinline__ void gemm_core(const ushort_t* Ab, const ushort_t* Wb,
                                          char* lds, int tid, f32x4 acc[MI][4]) {
    constexpr int K = 1024;
    constexpr int ABYTES = MI * 4096;          // A tile: MI*32 rows x 128B
    constexpr int TILE = ABYTES + 16384;       // + B tile (128 rows x 128B)
    int lane = tid & 63, wid = tid >> 6;
    int cl = lane & 15, gr = lane >> 4;
    int wm = (wid >> 1) * (MI * 16), wn = (wid & 1) * 64;
#pragma unroll
    for (int i = 0; i < MI; ++i)
#pragma unroll
        for (int j = 0; j < 4; ++j) acc[i][j] = (f32x4)0.0f;

    // hoisted per-thread staging offsets (only k0 varies per iter)
    int aOff[MI], aDst[MI], bOff[4], bDst[4];
#pragma unroll
    for (int iss = 0; iss < MI; ++iss) {
        int c = iss * 256 + tid;
        int r = c >> 3, kc = (c & 7) ^ (r & 7);
        aOff[iss] = r * K + kc * 8;
        aDst[iss] = c * 16;
    }
#pragma unroll
    for (int iss = 0; iss < 4; ++iss) {
        int c = iss * 256 + tid;
        int r = c >> 3, kc = (c & 7) ^ (r & 7);
        bOff[iss] = r * K + kc * 8;
        bDst[iss] = c * 16;
    }

    auto stage = [&](int kt, char* dst) {
        int k0 = kt * 64;
#pragma unroll
        for (int iss = 0; iss < MI; ++iss)
            gload_lds16(Ab + aOff[iss] + k0, dst + aDst[iss]);
#pragma unroll
        for (int iss = 0; iss < 4; ++iss)
            gload_lds16(Wb + bOff[iss] + k0, dst + ABYTES + bDst[iss]);
    };

    auto compute = [&](const char* cb) {
        const char* cA = cb;
        const char* cW = cb + ABYTES;
#pragma unroll
        for (int ks = 0; ks < 2; ++ks) {
            short8 af[MI], wf[4];
#pragma unroll
            for (int t = 0; t < MI; ++t)
                af[t] = lds_frag(cA, wm + t * 16 + cl, ks * 4 + gr);
#pragma unroll
            for (int t = 0; t < 4; ++t)
                wf[t] = lds_frag(cW, wn + t * 16 + cl, ks * 4 + gr);
#pragma unroll
            for (int i = 0; i < MI; ++i)
#pragma unroll
                for (int j = 0; j < 4; ++j)
                    acc[i][j] = mfma32(af[i], wf[j], acc[i][j]);
        }
    };

    if (DBUF) {
        stage(0, lds);
        __syncthreads();
        for (int kt = 0; kt < K / 64; ++kt) {
            char* cb = lds + (kt & 1) * TILE;
            if (kt < K / 64 - 1) stage(kt + 1, lds + ((kt + 1) & 1) * TILE);
            compute(cb);
            __syncthreads();   // drains prefetch (landed under compute) + guards buf reuse
        }
    } else {
        for (int kt = 0; kt < K / 64; ++kt) {
            stage(kt, lds);
            __syncthreads();
            compute(lds);
            __syncthreads();
        }
    }
}

// mode 0: bf16 out head-major [b,h,s,d]; mode 1: bf16 out [b,h,d,s]; mode 2: fp32 row-major
// Tile: (MI*32)x128. Grid (8, M/(MI*32), z). Bijective XCD swizzle over the flat block id.
template<int MI, int DBUF>
__global__ __launch_bounds__(256, 3)
void gemm3(const ushort_t* A0, const ushort_t* A1, const ushort_t* A2,
           const ushort_t* W0, const ushort_t* W1, const ushort_t* W2,
           const float* B0, const float* B1, const float* B2,
           void* O0, void* O1, void* O2, int mode_ovr, float scl0) {
    __shared__ char lds[(DBUF ? 2 : 1) * (MI * 4096 + 16384)];

    // XCD swizzle: consecutive logical ids land on one XCD; bx fastest (shared A panel)
    int gx = gridDim.x, gy = gridDim.y;
    int nwg = gx * gy * gridDim.z;
    int bid = blockIdx.x + gx * (blockIdx.y + gy * blockIdx.z);
    int nb = (bid & 7) * (nwg >> 3) + (bid >> 3);
    int bx = nb % gx;
    int t2 = nb / gx;
    int by = t2 % gy;
    int z = t2 / gy;

    const ushort_t* A = z == 0 ? A0 : z == 1 ? A1 : A2;
    const ushort_t* W = z == 0 ? W0 : z == 1 ? W1 : W2;
    const float* bias = z == 0 ? B0 : z == 1 ? B1 : B2;
    void* out = z == 0 ? O0 : z == 1 ? O1 : O2;
    int mode = mode_ovr >= 0 ? mode_ovr : (z == 2 ? 1 : 0);
    float scl = z == 0 ? scl0 : 1.0f;

    int tid = threadIdx.x, lane = tid & 63, wid = tid >> 6;
    int cl = lane & 15, gr = lane >> 4;
    int wm = (wid >> 1) * (MI * 16), wn = (wid & 1) * 64;
    int bm = by * (MI * 32), bn = bx * 128;

    f32x4 acc[MI][4];
    gemm_core<MI, DBUF>(A + (size_t)bm * 1024, W + (size_t)bn * 1024, lds, tid, acc);

#pragma unroll
    for (int j = 0; j < 4; ++j) {
        int n = bn + wn + j * 16 + cl;
        float bv = bias[n];
#pragma unroll
        for (int i = 0; i < MI; ++i) {
            int mbase = bm + wm + i * 16 + gr * 4;
            if (mode == 0) {
#pragma unroll
                for (int r = 0; r < 4; ++r) {
                    int m = mbase + r;
                    float v = (acc[i][j][r] + bv) * scl;
                    size_t idx = (((size_t)((m >> 11) * 16 + (n >> 6))) * 2048 + (m & 2047)) * 64 + (n & 63);
                    ((ushort_t*)out)[idx] = f2bf(v);
                }
            } else if (mode == 1) {
                us4 pk;
#pragma unroll
                for (int r = 0; r < 4; ++r) pk[r] = f2bf(acc[i][j][r] + bv);
                size_t idx = (((size_t)((mbase >> 11) * 16 + (n >> 6))) * 64 + (n & 63)) * 2048 + (mbase & 2047);
                *(us4*)((ushort_t*)out + idx) = pk;
            } else {
#pragma unroll
                for (int r = 0; r < 4; ++r)
                    ((float*)out)[(size_t)(mbase + r) * 1024 + n] = acc[i][j][r] + bv;
            }
        }
    }
}

// ---------------- fused masked attention v8b (round-13 proven: 58.8 us) ----------------
// grid 512 = (b,h)*16 q-tiles of 128 rows; 8 waves = 4 q-groups x 2 kv-halves.
// K and V both staged in LDS (2 streams x 2 bufs x 16KB = 64KB); deferred softmax,
// in-register P (truncation pack), ones-column MFMA row-sums, setprio on MFMA.
__global__ __launch_bounds__(512, 4)
void attn(const ushort_t* __restrict__ Q, const ushort_t* __restrict__ Kh,
          const ushort_t* __restrict__ Vt, const unsigned long long* __restrict__ PM,
          ushort_t* __restrict__ ctx) {
    constexpr int S = 2048;
    __shared__ char lds[65536];   // [2 streams][2 bufs][K 8KB | V 8KB]; reused for merge
    int tid = threadIdx.x, lane = tid & 63, wid = tid >> 6;
    int cl = lane & 15, gr = lane >> 4, c7 = cl & 7;
    int h2 = wid & 1;            // kv-half this wave computes
    int qg = wid >> 1;           // q-group 0..3

    int blk = (blockIdx.x & 7) * 64 + (blockIdx.x >> 3);
    int bh = blk >> 4, qt = blk & 15;
    int b = bh >> 4, h = bh & 15;
    const ushort_t* Qb = Q + (size_t)bh * S * 64;
    const ushort_t* Kb = Kh + (size_t)bh * S * 64;
    const ushort_t* Vb = Vt + (size_t)bh * 64 * S;
    int q0w = qt * 128 + qg * 32;

    short8 qreg[2][2];
#pragma unroll
    for (int qf = 0; qf < 2; ++qf)
#pragma unroll
        for (int ks = 0; ks < 2; ++ks)
            qreg[qf][ks] = *(const short8*)(Qb + (size_t)(q0w + qf * 16 + cl) * 64 + ks * 32 + gr * 8);

    f32x4 acc[2][4];
    f32x4 accl[2];
#pragma unroll
    for (int qf = 0; qf < 2; ++qf) {
        accl[qf] = (f32x4)0.0f;
#pragma unroll
        for (int df = 0; df < 4; ++df) acc[qf][df] = (f32x4)0.0f;
    }

    int hs = tid >> 8, stid = tid & 255;
    int kOff[2], vOff[2], dstL[2];
#pragma unroll
    for (int iss = 0; iss < 2; ++iss) {
        int L = iss * 256 + stid;
        int r = L >> 3, c = (L & 7) ^ (r & 7);
        kOff[iss] = r * 64 + c * 8;
        vOff[iss] = r * S + c * 8;
        dstL[iss] = L * 16;
    }
    char* sbase = lds + hs * 32768;

    int aK0 = cl * 128 + ((0 * 4 + gr) ^ c7) * 16;
    int aK1 = cl * 128 + ((1 * 4 + gr) ^ c7) * 16;
    int aV[4];
#pragma unroll
    for (int nf = 0; nf < 4; ++nf)
        aV[nf] = cl * 128 + (((2 * nf) + (gr >> 1)) ^ c7) * 16 + (gr & 1) * 8;

    const unsigned long long* pmq = PM + (size_t)b * 32 * 2048 + q0w + cl;

    short4v ones;
#pragma unroll
    for (int r = 0; r < 4; ++r) ones[r] = (short)0x3F80;   // bf16 1.0

    auto stage = [&](int T, int parity) {
        const ushort_t* Ks = Kb + (size_t)T * 4096;
        const ushort_t* Vs = Vb + (size_t)T * 64;
        char* dst = sbase + parity * 16384;
#pragma unroll
        for (int iss = 0; iss < 2; ++iss) {
            gload_lds16(Ks + kOff[iss], dst + dstL[iss]);
            gload_lds16(Vs + vOff[iss], dst + 8192 + dstL[iss]);
        }
    };

    stage(hs * 16, 0);
    __syncthreads();

    char* mybase = lds + h2 * 32768;
    for (int t = 0; t < 16; ++t) {
        char* cb = mybase + (t & 1) * 16384;
        if (t < 15) stage(hs * 16 + t + 1, (t + 1) & 1);

        int kvi = h2 * 16 + t;
        unsigned long long w0 = pmq[(size_t)kvi * 2048];
        unsigned long long w1 = pmq[(size_t)kvi * 2048 + 16];

        f32x4 sc[2][4];
        __builtin_amdgcn_s_setprio(1);
#pragma unroll
        for (int nf = 0; nf < 4; ++nf) {
            short8 k0 = *(const short8*)(cb + aK0 + nf * 2048);
            short8 k1 = *(const short8*)(cb + aK1 + nf * 2048);
#pragma unroll
            for (int qf = 0; qf < 2; ++qf) {
                f32x4 s = mfma32(k0, qreg[qf][0], (f32x4)0.0f);
                sc[qf][nf] = mfma32(k1, qreg[qf][1], s);
            }
        }
        __builtin_amdgcn_s_setprio(0);

        short4v pk[2][4];
#pragma unroll
        for (int qf = 0; qf < 2; ++qf) {
            unsigned long long ws = (qf == 0 ? w0 : w1) >> (gr * 4);
            uint32_t lo = (uint32_t)ws, hi = (uint32_t)(ws >> 32);
#pragma unroll
            for (int nf = 0; nf < 4; ++nf) {
                uint32_t wb = nf < 2 ? lo : hi;
                uint32_t u[4];
#pragma unroll
                for (int r = 0; r < 4; ++r) {
                    uint32_t bit = wb & (1u << ((nf & 1) * 16 + r));
                    float sel = bit ? sc[qf][nf][r] : -1.0e9f;
                    u[r] = fbits(fexp2(sel));          // truncation pack (no +0x8000)
                }
                union { uint32_t d[2]; short4v v; } pp;
                pp.d[0] = __builtin_amdgcn_perm(u[1], u[0], 0x07060302u);
                pp.d[1] = __builtin_amdgcn_perm(u[3], u[2], 0x07060302u);
                pk[qf][nf] = pp.v;
            }
        }

        __builtin_amdgcn_s_setprio(1);
#pragma unroll
        for (int nf = 0; nf < 4; ++nf) {
#pragma unroll
            for (int df = 0; df < 4; ++df) {
                short4v vf = *(const short4v*)(cb + 8192 + aV[nf] + df * 2048);
                acc[0][df] = mfma16(pk[0][nf], vf, acc[0][df]);
                acc[1][df] = mfma16(pk[1][nf], vf, acc[1][df]);
            }
            accl[0] = mfma16(pk[0][nf], ones, accl[0]);
            accl[1] = mfma16(pk[1][nf], ones, accl[1]);
        }
        __builtin_amdgcn_s_setprio(0);
        __syncthreads();
    }

    if (h2) {
        float* dst = (float*)(lds + qg * 10240 + lane * 160);
#pragma unroll
        for (int qf = 0; qf < 2; ++qf) {
#pragma unroll
            for (int df = 0; df < 4; ++df)
                *(f32x4*)(dst + qf * 16 + df * 4) = acc[qf][df];
            *(f32x4*)(dst + 32 + qf * 4) = accl[qf];
        }
    }
    __syncthreads();
    if (!h2) {
        const float* src = (const float*)(lds + qg * 10240 + lane * 160);
#pragma unroll
        for (int qf = 0; qf < 2; ++qf) {
#pragma unroll
            for (int df = 0; df < 4; ++df)
                acc[qf][df] += *(const f32x4*)(src + qf * 16 + df * 4);
            accl[qf] += *(const f32x4*)(src + 32 + qf * 4);
        }
#pragma unroll
        for (int qf = 0; qf < 2; ++qf) {
            float inv[4];
#pragma unroll
            for (int r = 0; r < 4; ++r) inv[r] = 1.0f / accl[qf][r];
#pragma unroll
            for (int df = 0; df < 4; ++df)
#pragma unroll
                for (int r = 0; r < 4; ++r) {
                    int q = q0w + qf * 16 + gr * 4 + r;
                    int d = df * 16 + cl;
                    ctx[((size_t)b * S + q) * 1024 + h * 64 + d] = f2bf(acc[qf][df][r] * inv[r]);
                }
        }
    }
}

// ---------------- launch ----------------
extern "C" void kernel_launch(void* const* d_in, const int* in_sizes, int n_in,
                              void* d_out, int out_size, void* d_ws, size_t ws_size,
                              hipStream_t stream) {
    const float* query = (const float*)d_in[0];
    const float* key   = (const float*)d_in[1];
    const float* value = (const float*)d_in[2];
    const int*   mask  = (const int*)d_in[3];
    const float* w_q = (const float*)d_in[4];
    const float* b_q = (const float*)d_in[5];
    const float* w_k = (const float*)d_in[6];
    const float* b_k = (const float*)d_in[7];
    const float* w_v = (const float*)d_in[8];
    const float* b_v = (const float*)d_in[9];
    const float* w_o = (const float*)d_in[10];
    const float* b_o = (const float*)d_in[11];

    char* ws = (char*)d_ws;
    const size_t MB = 1 << 20;
    ushort_t* xq  = (ushort_t*)(ws + 0 * MB);
    ushort_t* xk  = (ushort_t*)(ws + 8 * MB);
    ushort_t* xv  = (ushort_t*)(ws + 16 * MB);
    ushort_t* wq  = (ushort_t*)(ws + 24 * MB);
    ushort_t* wk  = (ushort_t*)(ws + 26 * MB);
    ushort_t* wv  = (ushort_t*)(ws + 28 * MB);
    ushort_t* wo  = (ushort_t*)(ws + 30 * MB);
    ushort_t* qhm = (ushort_t*)(ws + 32 * MB);
    ushort_t* khm = (ushort_t*)(ws + 40 * MB);
    ushort_t* vt  = (ushort_t*)(ws + 48 * MB);
    unsigned long long* pm = (unsigned long long*)(ws + 56 * MB);
    ushort_t* ctx = (ushort_t*)(ws + 0 * MB);   // alias xq (dead after QKV gemm)

    // fold 1/sqrt(D_K)=0.125 AND log2(e) into Q so softmax is a bare v_exp_f32
    const float QSCALE = 0.125f * 1.44269504088896f;

    prep_all<<<dim3(1024, 8), 256, 0, stream>>>(query, key, value, w_q, w_k, w_v, w_o,
                                                xq, xk, xv, wq, wk, wv, wo, mask, pm);

    // QKV: 128x128 tile, single-buffered m97 structure, 3 blocks/CU, XCD swizzle
    gemm3<4, 0><<<dim3(8, 32, 3), 256, 0, stream>>>(xq, xk, xv, wq, wk, wv, b_q, b_k, b_v,
                                                    qhm, khm, vt, -1, QSCALE);

    attn<<<512, 512, 0, stream>>>(qhm, khm, vt, pm, ctx);

    // O-proj: 64x128 tile, double-buffered prefetch (512-block grid can't feed MI=4)
    gemm3<2, 1><<<dim3(8, 64, 1), 256, 0, stream>>>(ctx, ctx, ctx, wo, wo, wo, b_o, b_o, b_o,
                                                    d_out, d_out, d_out, 2, 1.0f);
}